// Round 25
// baseline (120.359 us; speedup 1.0000x reference)
//
#include <hip/hip_runtime.h>
#include <hip/hip_fp8.h>
#include <stdint.h>
#include <math.h>

#define C_NUM 2048
#define N_TOT 4096
#define B_TOT 4096
#define KNOWN 1024

typedef __attribute__((ext_vector_type(4))) float f32x4;
typedef __attribute__((ext_vector_type(4))) int i32x4;
typedef __attribute__((ext_vector_type(8))) int i32x8;

__device__ __forceinline__ void gld16(const void* g, void* l) {
  __builtin_amdgcn_global_load_lds(
      (const __attribute__((address_space(1))) void*)g,
      (__attribute__((address_space(3))) void*)l, 16, 0, 0);
}

// ---- Kernel 1: transpose + fp8 convert + stats + sumexp init (R22) -------
__global__ __launch_bounds__(256) void transpose_stats_kernel(
    const float* __restrict__ prob,
    const float* __restrict__ prob_s,
    float* __restrict__ colsum,
    float* __restrict__ norm2,
    float* __restrict__ sumexp,
    uint8_t* __restrict__ Pn) {
  __shared__ float tile[64][68];
  const int tid = threadIdx.x;
  const int c0 = blockIdx.x * 64;       // class tile (0..4095)
  const int b0 = blockIdx.y * 256;      // batch super-tile
  const float* src = (c0 < C_NUM) ? prob : prob_s;
  const int colbase = (c0 & (C_NUM - 1));

  const int lrow = tid >> 4;            // load row 0..15 (+16c)
  const int f4c = tid & 15;
  const int ci = tid >> 2;              // class within tile 0..63
  const int qb = tid & 3;               // batch quarter within sub-tile

  float s = 0.f, s2 = 0.f;

#pragma unroll
  for (int st = 0; st < 4; ++st) {
    const int bs = b0 + st * 64;
#pragma unroll
    for (int c = 0; c < 4; ++c) {
      const float4 v = *(const float4*)(src + (size_t)(bs + lrow + 16 * c) * C_NUM +
                                        colbase + f4c * 4);
      *(float4*)&tile[lrow + 16 * c][f4c * 4] = v;
    }
    __syncthreads();

    uint8_t bytes[16];
#pragma unroll
    for (int k = 0; k < 16; ++k) {
      float v = tile[qb * 16 + k][ci];
      s += v;
      s2 += v * v;
      __hip_fp8_e4m3 q(v);
      bytes[k] = q.__x;
    }
    *(i32x4*)(Pn + (size_t)(c0 + ci) * B_TOT + bs + qb * 16) = *(i32x4*)bytes;
    __syncthreads();
  }

  s += __shfl_xor(s, 1);
  s += __shfl_xor(s, 2);
  s2 += __shfl_xor(s2, 1);
  s2 += __shfl_xor(s2, 2);
  if (qb == 0) {
    atomicAdd(&colsum[c0 + ci], s);
    atomicAdd(&norm2[c0 + ci], s2);
    if (blockIdx.y == 0)
      sumexp[c0 + ci] = (((c0 + ci) & 1024) == 0) ? 1023.0f : 0.0f;
  }
}

// ---- Kernel 2: PAIRED symmetric MX-fp8 GEMM + fused finalize -------------
// GEMM body R22/R24-VERBATIM (50.6 us, reproduced twice). NEW: the last
// block to finish (device-scope ticket) performs the finalize inline —
// deletes the separate single-block kernel + launch gap (~5 us tail).
__global__ __launch_bounds__(512) void simgemm_kernel(
    const uint8_t* __restrict__ Pn,
    const float* __restrict__ norm2,
    float* __restrict__ colsum,
    float* __restrict__ sumexp,
    float* __restrict__ pos,
    unsigned int* __restrict__ done,
    float* __restrict__ out) {
  __shared__ __align__(16) char lds_all[131072];  // group g at g*65536

  const int tid = threadIdx.x;
  const int g = tid >> 8;            // job group 0/1
  const int ti = tid & 255;          // thread within group
  const int l = ti & 63;
  const int w = ti >> 6;             // wave-in-group 0..3
  const int wr = w >> 1, wc = w & 1; // 2x2 wave grid
  char* const lds = lds_all + g * 65536;

  // job decode: m in [0,492). m<192: it=m/24, jt=8+m%24 (it<8 strip).
  // else triangular over it in [8,32): jt = it + t.
  const int m = 2 * blockIdx.x + g;
  int it, jt;
  if (m < 192) {
    it = m / 24;
    jt = 8 + (m - it * 24);
  } else {
    int t = m - 192;
    int ii = 0, rem = 24;
    while (t >= rem) { t -= rem; ++ii; --rem; }
    it = 8 + ii;
    jt = it + t;
  }
  const int ib = it * 128;
  const int jb = jt * 128;
  const bool diag = (it == jt);

  // staging (R15-verified): thread ti covers granules G = ti + 256c
  // (c=0..3): row = (ti>>3)+32c, phys slot = ti&7,
  // logical slot = (ti&7) ^ ((ti>>3)&7)  (32c == 0 mod 8).
  const int glog = (ti & 7) ^ ((ti >> 3) & 7);
  const char* gA = (const char*)Pn + (size_t)(ib + (ti >> 3)) * B_TOT + glog * 16;
  const char* gB = (const char*)Pn + (size_t)(jb + (ti >> 3)) * B_TOT + glog * 16;
  const int ldsOf = ti * 16;

  f32x4 acc[4][4];
#pragma unroll
  for (int a = 0; a < 4; ++a)
#pragma unroll
    for (int b = 0; b < 4; ++b)
      acc[a][b] = (f32x4){0.f, 0.f, 0.f, 0.f};

  // fragment geometry (R15-verified): rows of 128B; lane k-granules
  // lg = (l>>4)*2, lg+1; phys = lg ^ (l&7); partner = ^1.
  const int lx = l & 15;
  const int ra = wr * 64 + lx;
  const int rb = wc * 64 + lx;
  const int ph0 = ((((l >> 4) * 2) ^ (l & 7))) * 16;
  const int bofs = diag ? 0 : 16384;   // diag: B frags from A region

#define STAGE(buf, koff)                                                    \
  do {                                                                      \
    _Pragma("unroll")                                                       \
    for (int c = 0; c < 4; ++c)                                             \
      gld16(gA + (size_t)(32 * c) * B_TOT + (koff),                         \
            lds + (buf) * 32768 + c * 4096 + ldsOf);                        \
    if (!diag) {                                                            \
      _Pragma("unroll")                                                     \
      for (int c = 0; c < 4; ++c)                                           \
        gld16(gB + (size_t)(32 * c) * B_TOT + (koff),                       \
              lds + (buf) * 32768 + 16384 + c * 4096 + ldsOf);              \
    }                                                                       \
  } while (0)

  STAGE(0, 0);
  __syncthreads();

  int cur = 0;
  const int NT = B_TOT / 128;   // 32 K-steps of 128 bytes
  for (int kt = 0; kt < NT; ++kt) {
    if (kt + 1 < NT) STAGE(cur ^ 1, (kt + 1) * 128);

    const char* Abase = lds + cur * 32768;
    const char* Bbase = Abase + bofs;

    i32x8 af[4];
#pragma unroll
    for (int fm = 0; fm < 4; ++fm) {
      const char* p = Abase + (ra + fm * 16) * 128;
      i32x4 lo = *(const i32x4*)(p + ph0);
      i32x4 hi = *(const i32x4*)(p + (ph0 ^ 16));
      af[fm] = __builtin_shufflevector(lo, hi, 0, 1, 2, 3, 4, 5, 6, 7);
    }
    __builtin_amdgcn_s_setprio(1);
#pragma unroll
    for (int fn = 0; fn < 4; ++fn) {
      const char* p = Bbase + (rb + fn * 16) * 128;
      i32x4 lo = *(const i32x4*)(p + ph0);
      i32x4 hi = *(const i32x4*)(p + (ph0 ^ 16));
      i32x8 bf = __builtin_shufflevector(lo, hi, 0, 1, 2, 3, 4, 5, 6, 7);
#pragma unroll
      for (int fm = 0; fm < 4; ++fm)
        acc[fm][fn] = __builtin_amdgcn_mfma_scale_f32_16x16x128_f8f6f4(
            af[fm], bf, acc[fm][fn], 0, 0, 0, 0x7F7F7F7F, 0, 0x7F7F7F7F);
    }
    __builtin_amdgcn_s_setprio(0);
    __syncthreads();   // staging of next landed + reads of cur done
    cur ^= 1;
  }
#undef STAGE

  // ---- epilogue (R20-verified): v = 2 * dot * inv_i * inv_j ----
  float invj[4];
#pragma unroll
  for (int fn = 0; fn < 4; ++fn)
    invj[fn] = 1.0f / fmaxf(sqrtf(norm2[jb + wc * 64 + fn * 16 + lx]), 1e-8f);

  if (diag) {
#pragma unroll
    for (int fm = 0; fm < 4; ++fm) {
#pragma unroll
      for (int r = 0; r < 4; ++r) {
        const int i = ib + wr * 64 + fm * 16 + (l >> 4) * 4 + r;
        const float invi = 1.0f / fmaxf(sqrtf(norm2[i]), 1e-8f);
        float rs = 0.f;
#pragma unroll
        for (int fn = 0; fn < 4; ++fn) {
          const int j = jb + wc * 64 + fn * 16 + lx;
          float v = acc[fm][fn][r] * 2.0f * invi * invj[fn];
          if (j != i) rs += __expf(v);  // no masked entries in live diag tiles
        }
        rs += __shfl_xor(rs, 1);
        rs += __shfl_xor(rs, 2);
        rs += __shfl_xor(rs, 4);
        rs += __shfl_xor(rs, 8);
        if (lx == 0) atomicAdd(&sumexp[i], rs);
      }
    }
  } else {
    float cs[4] = {0.f, 0.f, 0.f, 0.f};
#pragma unroll
    for (int fm = 0; fm < 4; ++fm) {
#pragma unroll
      for (int r = 0; r < 4; ++r) {
        const int i = ib + wr * 64 + fm * 16 + (l >> 4) * 4 + r;
        const float invi = 1.0f / fmaxf(sqrtf(norm2[i]), 1e-8f);
        float rs = 0.f;
#pragma unroll
        for (int fn = 0; fn < 4; ++fn) {
          const int j = jb + wc * 64 + fn * 16 + lx;
          float v = acc[fm][fn][r] * 2.0f * invi * invj[fn];
          float e = __expf(v);
          if (j == (i ^ 2048)) {
            pos[i] = v;               // positive pair (symmetric value)
            pos[j] = v;
            rs += e;                  // exp(pos) in both denominators
            cs[fn] += e;
          } else {
            rs += e;                  // row-i never masked in live tiles
            cs[fn] += (((j & 1024) == 0) && (i < KNOWN)) ? 0.f : e;
          }
        }
        rs += __shfl_xor(rs, 1);
        rs += __shfl_xor(rs, 2);
        rs += __shfl_xor(rs, 4);
        rs += __shfl_xor(rs, 8);
        if (lx == 0) atomicAdd(&sumexp[i], rs);
      }
    }
#pragma unroll
    for (int fn = 0; fn < 4; ++fn) {
      cs[fn] += __shfl_xor(cs[fn], 16);
      cs[fn] += __shfl_xor(cs[fn], 32);
    }
    if (l < 16) {
#pragma unroll
      for (int fn = 0; fn < 4; ++fn)
        if (cs[fn] != 0.f)
          atomicAdd(&sumexp[jb + wc * 64 + fn * 16 + l], cs[fn]);
    }
  }

  // ---- last-block-done fused finalize ----
  __shared__ unsigned int ticket_sh;
  __shared__ float red[8];
  __threadfence();                    // epilogue writes visible device-wide
  __syncthreads();                    // whole block's epilogue complete
  if (tid == 0) ticket_sh = atomicAdd(done, 1u);
  __syncthreads();
  if (ticket_sh != 245u) return;      // not the last block
  __threadfence();                    // acquire: all other blocks' writes

  // volatile reads bypass L1 (epilogue data lives in L2/HBM)
  volatile const float* vsum = (volatile const float*)sumexp;
  volatile const float* vpos = (volatile const float*)pos;
  volatile const float* vcol = (volatile const float*)colsum;

  float ce = 0.f, t1 = 0.f, t2 = 0.f;
  for (int i = tid; i < N_TOT; i += 512) ce += logf(vsum[i]) - vpos[i];
  for (int c = tid; c < C_NUM; c += 512) t1 += vcol[c];
  for (int c = tid; c < C_NUM; c += 512) t2 += vcol[C_NUM + c];

#pragma unroll
  for (int mm = 32; mm >= 1; mm >>= 1) {
    ce += __shfl_xor(ce, mm);
    t1 += __shfl_xor(t1, mm);
    t2 += __shfl_xor(t2, mm);
  }
  __syncthreads();
  if ((tid & 63) == 0) red[tid >> 6] = ce;
  __syncthreads();
  if (tid == 0) { float r = 0.f; for (int k = 0; k < 8; ++k) r += red[k]; red[0] = r; }
  __syncthreads();
  const float ce_tot = red[0];
  __syncthreads();
  if ((tid & 63) == 0) red[tid >> 6] = t1;
  __syncthreads();
  if (tid == 0) { float r = 0.f; for (int k = 0; k < 8; ++k) r += red[k]; red[0] = r; }
  __syncthreads();
  const float t1_tot = red[0];
  __syncthreads();
  if ((tid & 63) == 0) red[tid >> 6] = t2;
  __syncthreads();
  if (tid == 0) { float r = 0.f; for (int k = 0; k < 8; ++k) r += red[k]; red[0] = r; }
  __syncthreads();
  const float t2_tot = red[0];
  __syncthreads();

  float e1 = 0.f, e2 = 0.f;
  for (int c = tid; c < C_NUM; c += 512) {
    float m1 = vcol[c] / t1_tot;
    e1 += m1 * logf(m1);
    float m2 = vcol[C_NUM + c] / t2_tot;
    e2 += m2 * logf(m2);
  }
#pragma unroll
  for (int mm = 32; mm >= 1; mm >>= 1) {
    e1 += __shfl_xor(e1, mm);
    e2 += __shfl_xor(e2, mm);
  }
  __syncthreads();
  if ((tid & 63) == 0) red[tid >> 6] = e1 + e2;
  __syncthreads();
  if (tid == 0) {
    float ee = 0.f;
    for (int k = 0; k < 8; ++k) ee += red[k];
    float reg = 2.0f * logf((float)C_NUM) + ee;
    out[0] = ce_tot / (float)N_TOT + reg;
  }
}

extern "C" void kernel_launch(void* const* d_in, const int* in_sizes, int n_in,
                              void* d_out, int out_size, void* d_ws, size_t ws_size,
                              hipStream_t stream) {
  const float* prob = (const float*)d_in[0];
  const float* prob_s = (const float*)d_in[1];
  float* out = (float*)d_out;

  char* ws = (char*)d_ws;
  uint8_t* Pn = (uint8_t*)ws;                                   // 16 MB fp8
  float* norm2 = (float*)(ws + (size_t)N_TOT * B_TOT);          // 4096 f32
  float* colsum = norm2 + N_TOT;                                // 4096 f32
  unsigned int* done = (unsigned int*)(colsum + N_TOT);         // 4 x u32
  float* sumexp = (float*)(done + 4);                           // 4096 f32
  float* pos = sumexp + N_TOT;                                  // 4096 f32

  // zero norm2 + colsum + done (contiguous); sumexp init in transpose
  hipMemsetAsync(norm2, 0, (size_t)(2 * N_TOT + 4) * sizeof(float), stream);

  transpose_stats_kernel<<<dim3(64, 16), 256, 0, stream>>>(
      prob, prob_s, colsum, norm2, sumexp, Pn);
  simgemm_kernel<<<246, 512, 0, stream>>>(Pn, norm2, colsum, sumexp, pos,
                                          done, out);
}

// Round 26
// 79.572 us; speedup vs baseline: 1.5126x; 1.5126x over previous
//
#include <hip/hip_runtime.h>
#include <hip/hip_fp8.h>
#include <stdint.h>
#include <math.h>

#define C_NUM 2048
#define N_TOT 4096
#define B_TOT 4096
#define KNOWN 1024

typedef __attribute__((ext_vector_type(4))) float f32x4;
typedef __attribute__((ext_vector_type(4))) int i32x4;
typedef __attribute__((ext_vector_type(8))) int i32x8;

__device__ __forceinline__ void gld16(const void* g, void* l) {
  __builtin_amdgcn_global_load_lds(
      (const __attribute__((address_space(1))) void*)g,
      (__attribute__((address_space(3))) void*)l, 16, 0, 0);
}

// ---- Kernel 1: transpose + fp8 convert + stats + sumexp init -------------
// Block: 64 classes x 256 batch (4 sub-tiles of 64). Stats accumulated in
// registers across sub-tiles -> ONE atomic pair per class per block-row.
// blockIdx.y==0 also initializes sumexp (masked rows pre-count 1023 =
// their 1023 x exp(0) masked negatives — R20-verified).
__global__ __launch_bounds__(256) void transpose_stats_kernel(
    const float* __restrict__ prob,
    const float* __restrict__ prob_s,
    float* __restrict__ colsum,
    float* __restrict__ norm2,
    float* __restrict__ sumexp,
    uint8_t* __restrict__ Pn) {
  __shared__ float tile[64][68];
  const int tid = threadIdx.x;
  const int c0 = blockIdx.x * 64;       // class tile (0..4095)
  const int b0 = blockIdx.y * 256;      // batch super-tile
  const float* src = (c0 < C_NUM) ? prob : prob_s;
  const int colbase = (c0 & (C_NUM - 1));

  const int lrow = tid >> 4;            // load row 0..15 (+16c)
  const int f4c = tid & 15;
  const int ci = tid >> 2;              // class within tile 0..63
  const int qb = tid & 3;               // batch quarter within sub-tile

  float s = 0.f, s2 = 0.f;

#pragma unroll
  for (int st = 0; st < 4; ++st) {
    const int bs = b0 + st * 64;
#pragma unroll
    for (int c = 0; c < 4; ++c) {
      const float4 v = *(const float4*)(src + (size_t)(bs + lrow + 16 * c) * C_NUM +
                                        colbase + f4c * 4);
      *(float4*)&tile[lrow + 16 * c][f4c * 4] = v;
    }
    __syncthreads();

    uint8_t bytes[16];
#pragma unroll
    for (int k = 0; k < 16; ++k) {
      float v = tile[qb * 16 + k][ci];
      s += v;
      s2 += v * v;
      __hip_fp8_e4m3 q(v);
      bytes[k] = q.__x;
    }
    *(i32x4*)(Pn + (size_t)(c0 + ci) * B_TOT + bs + qb * 16) = *(i32x4*)bytes;
    __syncthreads();
  }

  s += __shfl_xor(s, 1);
  s += __shfl_xor(s, 2);
  s2 += __shfl_xor(s2, 1);
  s2 += __shfl_xor(s2, 2);
  if (qb == 0) {
    atomicAdd(&colsum[c0 + ci], s);
    atomicAdd(&norm2[c0 + ci], s2);
    if (blockIdx.y == 0)
      sumexp[c0 + ci] = (((c0 + ci) & 1024) == 0) ? 1023.0f : 0.0f;
  }
}

// ---- Kernel 2: PAIRED symmetric MX-fp8 GEMM (16x16x128) + epilogue -------
// R22/R24-VERBATIM (best measured: simgemm 50.6 us, reproduced twice).
// 512 threads = TWO independent 4-wave R15 engines (group = tid>>8), each
// with its own 64KB LDS half and its own 128x128 tile job -> 2 waves/SIMD
// (measured optimum: 1 wave/SIMD = latency-exposed (R15, 68.8); 4
// waves/SIMD = LDS-BW-bound (R23, 53.3)). Live jobs: jt>=it minus fully-
// masked it<8&&jt<8 -> 492 jobs = 246 pair-blocks (single round).
// R25 lesson: do NOT fuse finalize (per-block device fence = +50 us).
__global__ __launch_bounds__(512) void simgemm_kernel(
    const uint8_t* __restrict__ Pn,
    const float* __restrict__ norm2,
    float* __restrict__ sumexp,
    float* __restrict__ pos) {
  __shared__ __align__(16) char lds_all[131072];  // group g at g*65536

  const int tid = threadIdx.x;
  const int g = tid >> 8;            // job group 0/1
  const int ti = tid & 255;          // thread within group
  const int l = ti & 63;
  const int w = ti >> 6;             // wave-in-group 0..3
  const int wr = w >> 1, wc = w & 1; // 2x2 wave grid
  char* const lds = lds_all + g * 65536;

  // job decode: m in [0,492). m<192: it=m/24, jt=8+m%24 (it<8 strip).
  // else triangular over it in [8,32): jt = it + t.
  const int m = 2 * blockIdx.x + g;
  int it, jt;
  if (m < 192) {
    it = m / 24;
    jt = 8 + (m - it * 24);
  } else {
    int t = m - 192;
    int ii = 0, rem = 24;
    while (t >= rem) { t -= rem; ++ii; --rem; }
    it = 8 + ii;
    jt = it + t;
  }
  const int ib = it * 128;
  const int jb = jt * 128;
  const bool diag = (it == jt);

  // staging (R15-verified): thread ti covers granules G = ti + 256c
  // (c=0..3): row = (ti>>3)+32c, phys slot = ti&7,
  // logical slot = (ti&7) ^ ((ti>>3)&7)  (32c == 0 mod 8).
  const int glog = (ti & 7) ^ ((ti >> 3) & 7);
  const char* gA = (const char*)Pn + (size_t)(ib + (ti >> 3)) * B_TOT + glog * 16;
  const char* gB = (const char*)Pn + (size_t)(jb + (ti >> 3)) * B_TOT + glog * 16;
  const int ldsOf = ti * 16;

  f32x4 acc[4][4];
#pragma unroll
  for (int a = 0; a < 4; ++a)
#pragma unroll
    for (int b = 0; b < 4; ++b)
      acc[a][b] = (f32x4){0.f, 0.f, 0.f, 0.f};

  // fragment geometry (R15-verified): rows of 128B; lane k-granules
  // lg = (l>>4)*2, lg+1; phys = lg ^ (l&7); partner = ^1.
  const int lx = l & 15;
  const int ra = wr * 64 + lx;
  const int rb = wc * 64 + lx;
  const int ph0 = ((((l >> 4) * 2) ^ (l & 7))) * 16;
  const int bofs = diag ? 0 : 16384;   // diag: B frags from A region

#define STAGE(buf, koff)                                                    \
  do {                                                                      \
    _Pragma("unroll")                                                       \
    for (int c = 0; c < 4; ++c)                                             \
      gld16(gA + (size_t)(32 * c) * B_TOT + (koff),                         \
            lds + (buf) * 32768 + c * 4096 + ldsOf);                        \
    if (!diag) {                                                            \
      _Pragma("unroll")                                                     \
      for (int c = 0; c < 4; ++c)                                           \
        gld16(gB + (size_t)(32 * c) * B_TOT + (koff),                       \
              lds + (buf) * 32768 + 16384 + c * 4096 + ldsOf);              \
    }                                                                       \
  } while (0)

  STAGE(0, 0);
  __syncthreads();

  int cur = 0;
  const int NT = B_TOT / 128;   // 32 K-steps of 128 bytes
  for (int kt = 0; kt < NT; ++kt) {
    if (kt + 1 < NT) STAGE(cur ^ 1, (kt + 1) * 128);

    const char* Abase = lds + cur * 32768;
    const char* Bbase = Abase + bofs;

    i32x8 af[4];
#pragma unroll
    for (int fm = 0; fm < 4; ++fm) {
      const char* p = Abase + (ra + fm * 16) * 128;
      i32x4 lo = *(const i32x4*)(p + ph0);
      i32x4 hi = *(const i32x4*)(p + (ph0 ^ 16));
      af[fm] = __builtin_shufflevector(lo, hi, 0, 1, 2, 3, 4, 5, 6, 7);
    }
    __builtin_amdgcn_s_setprio(1);
#pragma unroll
    for (int fn = 0; fn < 4; ++fn) {
      const char* p = Bbase + (rb + fn * 16) * 128;
      i32x4 lo = *(const i32x4*)(p + ph0);
      i32x4 hi = *(const i32x4*)(p + (ph0 ^ 16));
      i32x8 bf = __builtin_shufflevector(lo, hi, 0, 1, 2, 3, 4, 5, 6, 7);
#pragma unroll
      for (int fm = 0; fm < 4; ++fm)
        acc[fm][fn] = __builtin_amdgcn_mfma_scale_f32_16x16x128_f8f6f4(
            af[fm], bf, acc[fm][fn], 0, 0, 0, 0x7F7F7F7F, 0, 0x7F7F7F7F);
    }
    __builtin_amdgcn_s_setprio(0);
    __syncthreads();   // staging of next landed + reads of cur done
    cur ^= 1;
  }
#undef STAGE

  // ---- epilogue (R20-verified): v = 2 * dot * inv_i * inv_j ----
  float invj[4];
#pragma unroll
  for (int fn = 0; fn < 4; ++fn)
    invj[fn] = 1.0f / fmaxf(sqrtf(norm2[jb + wc * 64 + fn * 16 + lx]), 1e-8f);

  if (diag) {
#pragma unroll
    for (int fm = 0; fm < 4; ++fm) {
#pragma unroll
      for (int r = 0; r < 4; ++r) {
        const int i = ib + wr * 64 + fm * 16 + (l >> 4) * 4 + r;
        const float invi = 1.0f / fmaxf(sqrtf(norm2[i]), 1e-8f);
        float rs = 0.f;
#pragma unroll
        for (int fn = 0; fn < 4; ++fn) {
          const int j = jb + wc * 64 + fn * 16 + lx;
          float v = acc[fm][fn][r] * 2.0f * invi * invj[fn];
          if (j != i) rs += __expf(v);  // no masked entries in live diag tiles
        }
        rs += __shfl_xor(rs, 1);
        rs += __shfl_xor(rs, 2);
        rs += __shfl_xor(rs, 4);
        rs += __shfl_xor(rs, 8);
        if (lx == 0) atomicAdd(&sumexp[i], rs);
      }
    }
  } else {
    float cs[4] = {0.f, 0.f, 0.f, 0.f};
#pragma unroll
    for (int fm = 0; fm < 4; ++fm) {
#pragma unroll
      for (int r = 0; r < 4; ++r) {
        const int i = ib + wr * 64 + fm * 16 + (l >> 4) * 4 + r;
        const float invi = 1.0f / fmaxf(sqrtf(norm2[i]), 1e-8f);
        float rs = 0.f;
#pragma unroll
        for (int fn = 0; fn < 4; ++fn) {
          const int j = jb + wc * 64 + fn * 16 + lx;
          float v = acc[fm][fn][r] * 2.0f * invi * invj[fn];
          float e = __expf(v);
          if (j == (i ^ 2048)) {
            pos[i] = v;               // positive pair (symmetric value)
            pos[j] = v;
            rs += e;                  // exp(pos) in both denominators
            cs[fn] += e;
          } else {
            rs += e;                  // row-i never masked in live tiles
            cs[fn] += (((j & 1024) == 0) && (i < KNOWN)) ? 0.f : e;
          }
        }
        rs += __shfl_xor(rs, 1);
        rs += __shfl_xor(rs, 2);
        rs += __shfl_xor(rs, 4);
        rs += __shfl_xor(rs, 8);
        if (lx == 0) atomicAdd(&sumexp[i], rs);
      }
    }
#pragma unroll
    for (int fn = 0; fn < 4; ++fn) {
      cs[fn] += __shfl_xor(cs[fn], 16);
      cs[fn] += __shfl_xor(cs[fn], 32);
    }
    if (l < 16) {
#pragma unroll
      for (int fn = 0; fn < 4; ++fn)
        if (cs[fn] != 0.f)
          atomicAdd(&sumexp[jb + wc * 64 + fn * 16 + l], cs[fn]);
    }
  }
}

// ---- Kernel 3: finalize (1024 threads = 16 waves) -------------------------
__device__ float block_reduce_1024(float v, volatile float* red) {
#pragma unroll
  for (int m = 32; m >= 1; m >>= 1) v += __shfl_xor(v, m);
  __syncthreads();
  if ((threadIdx.x & 63) == 0) red[threadIdx.x >> 6] = v;
  __syncthreads();
  float r = 0.f;
#pragma unroll
  for (int k = 0; k < 16; ++k) r += red[k];
  return r;
}

__global__ __launch_bounds__(1024) void finalize_kernel(
    const float* __restrict__ colsum,
    const float* __restrict__ sumexp,
    const float* __restrict__ pos,
    float* __restrict__ out) {
  __shared__ float red[16];
  int t = threadIdx.x;
  float ce = 0.f, t1 = 0.f, t2 = 0.f;
  for (int i = t; i < N_TOT; i += 1024) ce += logf(sumexp[i]) - pos[i];
  for (int c = t; c < C_NUM; c += 1024) t1 += colsum[c];
  for (int c = t; c < C_NUM; c += 1024) t2 += colsum[C_NUM + c];
  ce = block_reduce_1024(ce, red);
  t1 = block_reduce_1024(t1, red);
  t2 = block_reduce_1024(t2, red);
  float e1 = 0.f, e2 = 0.f;
  for (int c = t; c < C_NUM; c += 1024) {
    float m = colsum[c] / t1;
    e1 += m * logf(m);
  }
  for (int c = t; c < C_NUM; c += 1024) {
    float m = colsum[C_NUM + c] / t2;
    e2 += m * logf(m);
  }
  e1 = block_reduce_1024(e1, red);
  e2 = block_reduce_1024(e2, red);
  if (t == 0) {
    float reg = logf((float)C_NUM) + e1 + logf((float)C_NUM) + e2;
    out[0] = ce / (float)N_TOT + reg;
  }
}

extern "C" void kernel_launch(void* const* d_in, const int* in_sizes, int n_in,
                              void* d_out, int out_size, void* d_ws, size_t ws_size,
                              hipStream_t stream) {
  const float* prob = (const float*)d_in[0];
  const float* prob_s = (const float*)d_in[1];
  float* out = (float*)d_out;

  char* ws = (char*)d_ws;
  uint8_t* Pn = (uint8_t*)ws;                                   // 16 MB fp8
  float* norm2 = (float*)(ws + (size_t)N_TOT * B_TOT);          // 4096 f32
  float* colsum = norm2 + N_TOT;                                // 4096 f32
  float* sumexp = colsum + N_TOT;                               // 4096 f32
  float* pos = sumexp + N_TOT;                                  // 4096 f32

  // zero norm2+colsum (contiguous); sumexp init is inside transpose_stats
  hipMemsetAsync(norm2, 0, (size_t)2 * N_TOT * sizeof(float), stream);

  transpose_stats_kernel<<<dim3(64, 16), 256, 0, stream>>>(
      prob, prob_s, colsum, norm2, sumexp, Pn);
  simgemm_kernel<<<246, 512, 0, stream>>>(Pn, norm2, sumexp, pos);
  finalize_kernel<<<1, 1024, 0, stream>>>(colsum, sumexp, pos, out);
}